// Round 3
// baseline (325.839 us; speedup 1.0000x reference)
//
#include <hip/hip_runtime.h>

typedef short s16x8 __attribute__((ext_vector_type(8)));
typedef float f32x4 __attribute__((ext_vector_type(4)));
typedef float f32x2 __attribute__((ext_vector_type(2)));

// ---------------- bf16 pack/unpack (RNE) ----------------

__device__ inline unsigned pack_bf16(float a, float b) {
  unsigned ua = __float_as_uint(a), ub = __float_as_uint(b);
  ua += 0x7fffu + ((ua >> 16) & 1u);
  ub += 0x7fffu + ((ub >> 16) & 1u);
  return (ua >> 16) | (ub & 0xffff0000u);
}
__device__ inline float unpack_lo(unsigned u) { return __uint_as_float(u << 16); }
__device__ inline float unpack_hi(unsigned u) { return __uint_as_float(u & 0xffff0000u); }

// ---------------- Bucketed CSR build (R8: random-line writes -> coalesced; kept) ----------------

__global__ void kb_count(const int* __restrict__ dst, int E,
                         int* __restrict__ bucket_cnt, int NB) {
  __shared__ int h[256];
  h[threadIdx.x] = 0;
  __syncthreads();
  int i = blockIdx.x * blockDim.x + threadIdx.x;
  int stride = gridDim.x * blockDim.x;
  for (; i < E; i += stride) atomicAdd(&h[dst[i] >> 9], 1);
  __syncthreads();
  if (threadIdx.x < NB && h[threadIdx.x]) atomicAdd(&bucket_cnt[threadIdx.x], h[threadIdx.x]);
}

__global__ void kb_scan(const int* __restrict__ bucket_cnt, int NB, int E,
                        int* __restrict__ bucket_start, int* __restrict__ bucket_cursor) {
  int tid = threadIdx.x, lane = tid & 63, w = tid >> 6;
  int v = (tid < NB) ? bucket_cnt[tid] : 0;
  int x = v;
#pragma unroll
  for (int off = 1; off < 64; off <<= 1) {
    int u = __shfl_up(x, off);
    if (lane >= off) x += u;
  }
  __shared__ int ws4[4];
  if (lane == 63) ws4[w] = x;
  __syncthreads();
  int add = 0;
  for (int k = 0; k < w; ++k) add += ws4[k];
  x += add;
  int excl = x - v;
  if (tid < NB) {
    bucket_start[tid] = excl;
    bucket_cursor[tid] = excl;
  }
  if (tid == 0) bucket_start[NB] = E;
}

__global__ __launch_bounds__(256) void kb_scatter(const int* __restrict__ src,
                                                  const int* __restrict__ dst, int E,
                                                  int* __restrict__ bucket_cursor,
                                                  unsigned* __restrict__ pairs) {
  constexpr int T = 16;
  __shared__ int bin_cnt[256], bin_base[256];
  bin_cnt[threadIdx.x] = 0;
  __syncthreads();
  int base = blockIdx.x * (256 * T);
  unsigned u[T];
  int bb[T], slot[T];
#pragma unroll
  for (int t = 0; t < T; ++t) {
    int e = base + t * 256 + threadIdx.x;
    if (e < E) {
      int s = src[e], d = dst[e];
      bb[t] = d >> 9;
      u[t] = (unsigned)s | ((unsigned)(d & 511) << 17);
      slot[t] = atomicAdd(&bin_cnt[bb[t]], 1);
    } else {
      bb[t] = -1;
    }
  }
  __syncthreads();
  if (bin_cnt[threadIdx.x] > 0)
    bin_base[threadIdx.x] = atomicAdd(&bucket_cursor[threadIdx.x], bin_cnt[threadIdx.x]);
  __syncthreads();
#pragma unroll
  for (int t = 0; t < T; ++t)
    if (bb[t] >= 0) pairs[bin_base[bb[t]] + slot[t]] = u[t];
}

__global__ __launch_bounds__(256) void kc_csr(const unsigned* __restrict__ pairs,
                                              const int* __restrict__ bucket_start,
                                              int N, float* __restrict__ dinv,
                                              int* __restrict__ row_start,
                                              int* __restrict__ deg,
                                              int* __restrict__ col) {
  int b = blockIdx.x;
  int pbase = bucket_start[b], m = bucket_start[b + 1] - pbase;
  int tid = threadIdx.x, lane = tid & 63, w = tid >> 6;
  __shared__ int cnt[512], cur[512];
  __shared__ int ws4[4];
  cnt[tid] = 0;
  cnt[tid + 256] = 0;
  __syncthreads();
  for (int i = tid; i < m; i += 256) atomicAdd(&cnt[pairs[pbase + i] >> 17], 1);
  __syncthreads();
  int c0 = cnt[2 * tid], c1 = cnt[2 * tid + 1];
  int p = c0 + c1, x = p;
#pragma unroll
  for (int off = 1; off < 64; off <<= 1) {
    int uu = __shfl_up(x, off);
    if (lane >= off) x += uu;
  }
  if (lane == 63) ws4[w] = x;
  __syncthreads();
  int add = 0;
  for (int k = 0; k < w; ++k) add += ws4[k];
  x += add;
  int xe = x - p;
  cur[2 * tid] = xe;
  cur[2 * tid + 1] = xe + c0;
  int n0 = b * 512 + 2 * tid;
  if (n0 < N) {
    deg[n0] = c0;
    dinv[n0] = rsqrtf((float)(c0 + 1));
    row_start[n0] = pbase + xe;
  }
  if (n0 + 1 < N) {
    deg[n0 + 1] = c1;
    dinv[n0 + 1] = rsqrtf((float)(c1 + 1));
    row_start[n0 + 1] = pbase + xe + c0;
  }
  __syncthreads();
  for (int i = tid; i < m; i += 256) {
    unsigned uu = pairs[pbase + i];
    int pos = atomicAdd(&cur[uu >> 17], 1);
    col[pbase + pos] = (int)(uu & 131071u);
  }
}

// ---------------- W transpose + bf16 pack: WT[n][kd] = (bf16 W[2kd][n], bf16 W[2kd+1][n]) ----------------

__global__ void kw_trans(const float* __restrict__ W, int NC, int NT,
                         unsigned* __restrict__ WT) {
  int id = blockIdx.x * 256 + threadIdx.x;
  if (id >= NT * 64) return;
  int n = id >> 6, kd = id & 63;
  float a = 0.f, b = 0.f;
  if (n < NC) {
    a = W[(2 * kd) * NC + n];
    b = W[(2 * kd + 1) * NC + n];
  }
  WT[id] = pack_bf16(a, b);
}

// ---------------- MFMA GEMM: G[r,c] = bf16(dinv[r] * sum_k A[r,k]*W[k,c]) ----------------
// 16x16x32 bf16 MFMA, fp32 acc. Block 256 = 4 waves; block tile M=64.
// Verified layouts (m89/m120): A[m=lane&15][k=quad*8+j]; B[k=quad*8+j][n=lane&15];
// D[n=lane&15][m=quad*4+reg]. LDS rows padded to 68 uints.
// R12: SLICED output option -> g1 stored slice-major [slice=t][node][8 uints]
// so k_agg1 can partition the 25.6MB working set into 8x 3.2MB L2-resident
// slices (one per XCD). FETCH_SIZE evidence: 192MB = N*256B*8 XCDs (full
// replication into every XCD L2).

template <int NTILES, int GSTRIDE, int NCOLS, bool A_FP32, bool SLICED>
__global__ __launch_bounds__(256, 4) void k_gemm_mfma(const void* __restrict__ Ain,
                                                      const unsigned* __restrict__ WT,
                                                      const float* __restrict__ dinv,
                                                      unsigned* __restrict__ G, int N) {
  __shared__ unsigned Ws[NTILES * 16 * 68];
  __shared__ unsigned As[64 * 68];

  const int tid = threadIdx.x;
  const int row0 = blockIdx.x * 64;

  constexpr int WV2 = NTILES * 16 * 32;  // uint2 count
  const uint2* WT2 = (const uint2*)WT;
#pragma unroll
  for (int i = tid; i < WV2; i += 256) {
    int r = i >> 5, kd2 = i & 31;
    *(uint2*)&Ws[r * 68 + kd2 * 2] = WT2[i];
  }

  if (A_FP32) {
    const float4* X4 = (const float4*)Ain + (size_t)row0 * 32;
#pragma unroll
    for (int i = tid; i < 2048; i += 256) {
      int r = i >> 5, c4 = i & 31;
      uint2 o = {0u, 0u};
      if (row0 + r < N) {
        float4 xv = X4[i];
        o.x = pack_bf16(xv.x, xv.y);
        o.y = pack_bf16(xv.z, xv.w);
      }
      *(uint2*)&As[r * 68 + c4 * 2] = o;
    }
  } else {
    const uint2* H2 = (const uint2*)Ain + (size_t)row0 * 32;
#pragma unroll
    for (int i = tid; i < 2048; i += 256) {
      int r = i >> 5, kd2 = i & 31;
      uint2 o = {0u, 0u};
      if (row0 + r < N) o = H2[i];
      *(uint2*)&As[r * 68 + kd2 * 2] = o;
    }
  }
  __syncthreads();

  const int w = tid >> 6, lane = tid & 63;
  const int quad = lane >> 4, n16 = lane & 15;

  f32x4 acc[NTILES];
#pragma unroll
  for (int t = 0; t < NTILES; ++t) acc[t] = {0.f, 0.f, 0.f, 0.f};

  const char* Ab = (const char*)As + (w * 16 + n16) * 272 + quad * 16;
  const char* Bb = (const char*)Ws + n16 * 272 + quad * 16;
#pragma unroll
  for (int s = 0; s < 4; ++s) {
    s16x8 a = *(const s16x8*)(Ab + s * 64);
#pragma unroll
    for (int t = 0; t < NTILES; ++t) {
      s16x8 b = *(const s16x8*)(Bb + t * 16 * 272 + s * 64);
      acc[t] = __builtin_amdgcn_mfma_f32_16x16x32_bf16(a, b, acc[t], 0, 0, 0);
    }
  }

#pragma unroll
  for (int reg = 0; reg < 4; ++reg) {
    int r = row0 + w * 16 + quad * 4 + reg;
    float dv = (r < N) ? dinv[r] : 0.f;
#pragma unroll
    for (int t = 0; t < NTILES; ++t) {
      float v = acc[t][reg] * dv;
      float vp = __shfl_xor(v, 1);
      int colc = t * 16 + n16;
      if ((n16 & 1) == 0 && colc < NCOLS && r < N) {
        size_t addr = SLICED ? ((size_t)t * (size_t)N + (size_t)r) * 8 + (n16 >> 1)
                             : (size_t)r * GSTRIDE + t * 8 + (n16 >> 1);
        G[addr] = pack_bf16(v, vp);
      }
    }
  }
}

// ---------------- Aggregation 1: h2 = bf16(relu(dinv[n]*(g1[n]+sum g1[nbr]) + b1)) ----------------
// R12 redesign. Evidence: FETCH_SIZE 192MB == N*256B*8 XCDs (g1 replicated into
// every XCD L2); two different kernel structures both stuck at ~64us / 3.49TB/s.
// Fix: g1 is slice-major [8][N][32B]; block handles slice s = blockIdx&7 ->
// lands on XCD s (dispatch round-robin heuristic; correctness-independent).
// Per-XCD working set = 3.2MB -> L2-resident. Geometry: one lane-PAIR per node
// (32 nodes/wave), serial edge loop, lane h owns 16B of the 32B slice.
// No cross-lane reduction, no shfl col distribution.

__global__ __launch_bounds__(256) void k_agg1(const unsigned* __restrict__ g1s,
                                              const int* __restrict__ row_start,
                                              const int* __restrict__ deg,
                                              const int* __restrict__ col,
                                              const float* __restrict__ dinv,
                                              const float* __restrict__ b1,
                                              unsigned* __restrict__ h2, int N) {
  const int s = blockIdx.x & 7;       // slice == XCD (heuristic)
  const int chunk = blockIdx.x >> 3;
  const int lane = threadIdx.x & 63;
  const int wv = threadIdx.x >> 6;
  const int p = lane >> 1, h = lane & 1;
  const int node = chunk * 128 + wv * 32 + p;
  if (node >= N) return;  // no cross-lane ops below; safe divergent exit
  const unsigned hb = (unsigned)h << 4;  // 0 or 16 bytes
  const char* __restrict__ sb = (const char*)g1s + (size_t)s * (size_t)N * 32u;

  f32x2 a0 = {0.f, 0.f}, a1 = {0.f, 0.f}, a2 = {0.f, 0.f}, a3 = {0.f, 0.f};

#define ACC4(U)                                         \
  a0 += (f32x2){unpack_lo((U).x), unpack_hi((U).x)};    \
  a1 += (f32x2){unpack_lo((U).y), unpack_hi((U).y)};    \
  a2 += (f32x2){unpack_lo((U).z), unpack_hi((U).z)};    \
  a3 += (f32x2){unpack_lo((U).w), unpack_hi((U).w)};

  // self-loop
  {
    uint4 su = *(const uint4*)(sb + ((((unsigned)node) << 5) | hb));
    ACC4(su);
  }

  const int start = row_start[node], cnt = deg[node];
  const int* __restrict__ cp = col + start;
  int j = 0;
  for (; j + 4 <= cnt; j += 4) {
    int c0 = cp[j], c1 = cp[j + 1], c2 = cp[j + 2], c3 = cp[j + 3];
    uint4 u0 = *(const uint4*)(sb + ((((unsigned)c0) << 5) | hb));
    uint4 u1 = *(const uint4*)(sb + ((((unsigned)c1) << 5) | hb));
    uint4 u2 = *(const uint4*)(sb + ((((unsigned)c2) << 5) | hb));
    uint4 u3 = *(const uint4*)(sb + ((((unsigned)c3) << 5) | hb));
    ACC4(u0);
    ACC4(u1);
    ACC4(u2);
    ACC4(u3);
  }
  for (; j < cnt; ++j) {
    int c = cp[j];
    uint4 u = *(const uint4*)(sb + ((((unsigned)c) << 5) | hb));
    ACC4(u);
  }
#undef ACC4

  const float dn = dinv[node];
  const float2* __restrict__ bp = (const float2*)b1 + (s * 8 + h * 4);
  float2 b0 = bp[0], b1v = bp[1], b2v = bp[2], b3v = bp[3];
  uint4 o;
  o.x = pack_bf16(fmaxf(fmaf(a0.x, dn, b0.x), 0.f), fmaxf(fmaf(a0.y, dn, b0.y), 0.f));
  o.y = pack_bf16(fmaxf(fmaf(a1.x, dn, b1v.x), 0.f), fmaxf(fmaf(a1.y, dn, b1v.y), 0.f));
  o.z = pack_bf16(fmaxf(fmaf(a2.x, dn, b2v.x), 0.f), fmaxf(fmaf(a2.y, dn, b2v.y), 0.f));
  o.w = pack_bf16(fmaxf(fmaf(a3.x, dn, b3v.x), 0.f), fmaxf(fmaf(a3.y, dn, b3v.y), 0.f));
  *(uint4*)(h2 + (size_t)node * 64 + s * 8 + h * 4) = o;
}

// ---------------- Aggregation 2: out = dinv[n]*(g2[n] + sum g2[nbr]) + b2, C=40 ----------------
// g2 packed bf16: 20 uints/row. 3 nodes per wave (60/64 lanes):
// lane = sub*20 + f, 3x outstanding gathers per wave.

__global__ void k_agg2(const unsigned* __restrict__ g2, const int* __restrict__ row_start,
                       const int* __restrict__ deg, const int* __restrict__ col,
                       const float* __restrict__ dinv, const float* __restrict__ b2,
                       float* __restrict__ out, int N) {
  int lane = threadIdx.x & 63;
  int sub = lane / 20;            // 0..2 active, 3 idle
  int f = lane - sub * 20;        // 0..19
  int node = (blockIdx.x * 4 + (threadIdx.x >> 6)) * 3 + sub;
  if (sub >= 3 || node >= N) return;
  unsigned su = g2[(size_t)node * 20 + f];
  float ax = unpack_lo(su), ay = unpack_hi(su);
  int start = row_start[node], cnt = deg[node];
  int j = 0;
  for (; j + 8 <= cnt; j += 8) {
    unsigned u[8];
#pragma unroll
    for (int t = 0; t < 8; ++t)
      u[t] = g2[(size_t)col[start + j + t] * 20 + f];
#pragma unroll
    for (int t = 0; t < 8; ++t) {
      ax += unpack_lo(u[t]);
      ay += unpack_hi(u[t]);
    }
  }
  for (; j + 4 <= cnt; j += 4) {
    unsigned u[4];
#pragma unroll
    for (int t = 0; t < 4; ++t)
      u[t] = g2[(size_t)col[start + j + t] * 20 + f];
#pragma unroll
    for (int t = 0; t < 4; ++t) {
      ax += unpack_lo(u[t]);
      ay += unpack_hi(u[t]);
    }
  }
  for (; j < cnt; ++j) {
    unsigned u = g2[(size_t)col[start + j] * 20 + f];
    ax += unpack_lo(u);
    ay += unpack_hi(u);
  }
  float dn = dinv[node];
  float2 o;
  o.x = fmaf(ax, dn, b2[2 * f]);
  o.y = fmaf(ay, dn, b2[2 * f + 1]);
  *(float2*)&out[(size_t)node * 40 + 2 * f] = o;
}

// ---------------- launch ----------------

extern "C" void kernel_launch(void* const* d_in, const int* in_sizes, int n_in,
                              void* d_out, int out_size, void* d_ws, size_t ws_size,
                              hipStream_t stream) {
  const float* x = (const float*)d_in[0];
  const int* ei = (const int*)d_in[1];   // int64 in reference -> int32 on device
  const float* W1 = (const float*)d_in[2];
  const float* b1 = (const float*)d_in[3];
  const float* W2 = (const float*)d_in[4];
  const float* b2 = (const float*)d_in[5];

  const int F = in_sizes[3];       // 128
  const int N = in_sizes[0] / F;   // 100000
  const int E = in_sizes[1] / 2;   // 1600000
  const int* esrc = ei;
  const int* edst = ei + E;
  const int NB = (N + 511) / 512;  // 196

  // workspace layout (bytes):
  char* ws = (char*)d_ws;
  int* bucket_cnt = (int*)(ws + 0);
  int* bucket_start = (int*)(ws + 4096);
  int* bucket_cursor = (int*)(ws + 8192);
  unsigned* w1t = (unsigned*)(ws + 16384);
  unsigned* w2t = (unsigned*)(ws + 49152);
  float* dinv = (float*)(ws + 65536);
  int* row_start = (int*)(ws + 466944);
  int* deg = (int*)(ws + 868352);
  unsigned* pairs = (unsigned*)(ws + 1269760);
  int* colx = (int*)(ws + 7669760);
  unsigned* g1 = (unsigned*)(ws + 14073856);
  unsigned* h2 = (unsigned*)(ws + 39673856);
  unsigned* g2 = g1;  // g1 is dead after k_agg1

  hipMemsetAsync(bucket_cnt, 0, 1024, stream);

  kb_count<<<256, 256, 0, stream>>>(edst, E, bucket_cnt, NB);
  kb_scan<<<1, 256, 0, stream>>>(bucket_cnt, NB, E, bucket_start, bucket_cursor);
  kb_scatter<<<(E + 4095) / 4096, 256, 0, stream>>>(esrc, edst, E, bucket_cursor, pairs);
  kc_csr<<<NB, 256, 0, stream>>>(pairs, bucket_start, N, dinv, row_start, deg, colx);

  kw_trans<<<32, 256, 0, stream>>>(W1, 128, 128, w1t);
  kw_trans<<<12, 256, 0, stream>>>(W2, 40, 48, w2t);

  const int gblocks = (N + 63) / 64;  // 1563
  // Layer 1: NTILES=8 (NC=128), A = x fp32, SLICED g1 output.
  k_gemm_mfma<8, 64, 128, true, true><<<gblocks, 256, 0, stream>>>(x, w1t, dinv, g1, N);
  // agg1: slice-partitioned, 128 nodes/block, 8 slice-blocks per chunk.
  const int chunks = (N + 127) / 128;  // 782
  k_agg1<<<chunks * 8, 256, 0, stream>>>(g1, row_start, deg, colx, dinv, b1, h2, N);
  // Layer 2: NTILES=3 (NC=40, padded 48), A = h2 bf16, row-major g2 (stride 20).
  k_gemm_mfma<3, 20, 40, false, false><<<gblocks, 256, 0, stream>>>(h2, w2t, dinv, g2, N);
  // agg2: 12 nodes per block (4 waves x 3 nodes).
  k_agg2<<<(N + 11) / 12, 256, 0, stream>>>(g2, row_start, deg, colx, dinv, b2,
                                            (float*)d_out, N);
}